// Round 10
// baseline (220.038 us; speedup 1.0000x reference)
//
#include <hip/hip_runtime.h>

typedef unsigned short u16;
typedef __attribute__((ext_vector_type(8))) short bf16x8;   // 8 bf16 in 4 VGPRs
typedef __attribute__((ext_vector_type(4))) float f32x4;

#define CST 0.18033688011112042f  // 0.125 * log2(e)

__device__ inline u16 f2bf(float f) {
    unsigned u;
    __builtin_memcpy(&u, &f, 4);
    unsigned r = (u + 0x7FFF + ((u >> 16) & 1)) >> 16;   // RNE
    return (u16)r;
}
__device__ inline unsigned pack2(float lo, float hi) {
    return (unsigned)f2bf(lo) | ((unsigned)f2bf(hi) << 16);
}
__device__ inline unsigned fbits(float f) {
    unsigned u;
    __builtin_memcpy(&u, &f, 4);
    return u;
}
__device__ inline f32x4 fzero() {
    f32x4 z = {0.f, 0.f, 0.f, 0.f};
    return z;
}
__device__ inline f32x4 mfma16(bf16x8 a, bf16x8 b, f32x4 c) {
    return __builtin_amdgcn_mfma_f32_16x16x32_bf16(a, b, c, 0, 0, 0);
}

// async global->LDS, 16B per lane; lds dst = wave-uniform base + lane*16
__device__ inline void gld_lds16(const u16* g, u16* l) {
    __builtin_amdgcn_global_load_lds(
        reinterpret_cast<const __attribute__((address_space(1))) unsigned int*>(
            reinterpret_cast<uintptr_t>(g)),
        reinterpret_cast<__attribute__((address_space(3))) unsigned int*>(
            static_cast<unsigned int>(reinterpret_cast<uintptr_t>(l))),
        16, 0, 0);
}

// ---------------------------------------------------------------------------
// prep: fused  (a) w_qkv transpose fp32->bf16  (b) w_o transpose
//              (c) x fp32->bf16 flat convert        (validated r9)
// ---------------------------------------------------------------------------
#define NB_WQKV (72 * 24)   // 2304/32 x 768/32
#define NB_WO   (24 * 24)
#define NB_CVT  (4096 * 768 / 2048)

__global__ __launch_bounds__(256) void prep(const float* __restrict__ x,
                                            const float* __restrict__ w_qkv,
                                            const float* __restrict__ w_o,
                                            u16* __restrict__ xb,
                                            u16* __restrict__ wqkvT,
                                            u16* __restrict__ woT) {
    __shared__ float tile[32][33];
    int bid = blockIdx.x;
    int t = threadIdx.x;
    if (bid < NB_WQKV + NB_WO) {
        const float* in;
        u16* out;
        int bx, by, R, C;
        if (bid < NB_WQKV) {
            in = w_qkv; out = wqkvT; R = 768; C = 2304;
            bx = bid % 72; by = bid / 72;
        } else {
            int b2 = bid - NB_WQKV;
            in = w_o; out = woT; R = 768; C = 768;
            bx = b2 % 24; by = b2 / 24;
        }
        int c0 = bx * 32, r0 = by * 32;
        int tx = t & 31, ty = t >> 5;  // 32 x 8
#pragma unroll
        for (int j = 0; j < 32; j += 8)
            tile[ty + j][tx] = in[(size_t)(r0 + ty + j) * C + c0 + tx];
        __syncthreads();
#pragma unroll
        for (int j = 0; j < 32; j += 8)
            out[(size_t)(c0 + ty + j) * R + r0 + tx] = f2bf(tile[tx][ty + j]);
    } else {
        int i = (bid - NB_WQKV - NB_WO) * 2048 + t * 8;
        float4 a = *(const float4*)(x + i);
        float4 b = *(const float4*)(x + i + 4);
        uint4 w;
        w.x = pack2(a.x, a.y);
        w.y = pack2(a.z, a.w);
        w.z = pack2(b.x, b.y);
        w.w = pack2(b.z, b.w);
        *(uint4*)(xb + i) = w;
    }
}

// ---------------------------------------------------------------------------
// V pre-transpose with per-32-key permutation matched to the in-register
// P fragment: within each 32-key group, natural k (= st*16 + quad*4 + r)
// maps to k' = quad*8 + st*4 + r.   (validated r8/r9)
// ---------------------------------------------------------------------------
__global__ __launch_bounds__(256) void vtrans(const u16* __restrict__ qkv,
                                              u16* __restrict__ vt) {
    __shared__ u16 T[64 * 136];  // [dh][key'] padded
    int t = threadIdx.x;
    int h = blockIdx.y, kv0 = blockIdx.x * 128;
    {
        int key = t >> 1, ch = (t & 1) * 32;
        const u16* vp = qkv + (size_t)(kv0 + key) * 2304 + 1536 + h * 64 + ch;
        u16 tmp[32];
        *(uint4*)&tmp[0]  = *(const uint4*)vp;
        *(uint4*)&tmp[8]  = *(const uint4*)(vp + 8);
        *(uint4*)&tmp[16] = *(const uint4*)(vp + 16);
        *(uint4*)&tmp[24] = *(const uint4*)(vp + 24);
        int k5 = key & 31, grp = key >> 5;
        int kp = (grp << 5) | (((k5 >> 2) & 3) << 3) | ((k5 >> 4) << 2) | (k5 & 3);
#pragma unroll
        for (int j = 0; j < 32; j++) T[(ch + j) * 136 + kp] = tmp[j];
    }
    __syncthreads();
    {
        int dh = t >> 2, kc = (t & 3) * 32;
        uint4 o0 = *(const uint4*)&T[dh * 136 + kc];
        uint4 o1 = *(const uint4*)&T[dh * 136 + kc + 8];
        uint4 o2 = *(const uint4*)&T[dh * 136 + kc + 16];
        uint4 o3 = *(const uint4*)&T[dh * 136 + kc + 24];
        u16* op = vt + ((size_t)(h * 64 + dh)) * 4096 + kv0 + kc;
        *(uint4*)op = o0;
        *(uint4*)(op + 8) = o1;
        *(uint4*)(op + 16) = o2;
        *(uint4*)(op + 24) = o3;
    }
}

// ---------------------------------------------------------------------------
// C[M,N] = A[M,K] @ Bt[N,K]^T + bias[N].  A,Bt bf16; bias fp32; C f32/bf16.
// MT x 128 tile, BK=32, global_load_lds(16B) + XOR-swizzled LDS (r9).
// ---------------------------------------------------------------------------
template <int MT, bool OUT_F32, bool SCALE_Q>
__global__ __launch_bounds__(256) void gemm_bt(const u16* __restrict__ A,
                                               const u16* __restrict__ Bt,
                                               const float* __restrict__ bias,
                                               void* __restrict__ Cv,
                                               int M, int N, int K) {
    constexpr int MI = MT / 32;   // per-wave m-tiles (4 or 2)
    constexpr int NA = MT / 64;   // A staging insts per wave (2 or 1)
    __shared__ u16 As[MT * 32];
    __shared__ u16 Bs[128 * 32];

    int t = threadIdx.x;
    int wave = t >> 6, lane = t & 63, quad = lane >> 4, l16 = lane & 15;
    int mbase = blockIdx.y * MT, nbase = blockIdx.x * 128;
    int mw = (wave & 1) * (MT / 2), nw = (wave >> 1) * 64;

    f32x4 acc[MI][4];
#pragma unroll
    for (int i = 0; i < MI; i++)
#pragma unroll
        for (int j = 0; j < 4; j++) acc[i][j] = fzero();

    int xqs = (lane & 3) ^ ((lane >> 3) & 3);
    const u16* AgL[NA];
    u16* AsL[NA];
#pragma unroll
    for (int j = 0; j < NA; j++) {
        int rl = wave * (MT / 4) + j * 16 + (lane >> 2);
        AgL[j] = A + (size_t)(mbase + rl) * K + xqs * 8;
        AsL[j] = As + wave * (MT / 4) * 32 + j * 512;  // wave-uniform
    }
    const u16* BgL[2];
    u16* BsL[2];
#pragma unroll
    for (int j = 0; j < 2; j++) {
        int rl = wave * 32 + j * 16 + (lane >> 2);
        BgL[j] = Bt + (size_t)(nbase + rl) * K + xqs * 8;
        BsL[j] = Bs + wave * 1024 + j * 512;
    }

    int xq = quad ^ ((l16 >> 1) & 3);
    int afo[MI], bfo[4];
#pragma unroll
    for (int i = 0; i < MI; i++) afo[i] = (mw + i * 16 + l16) * 32 + xq * 8;
#pragma unroll
    for (int i = 0; i < 4; i++) bfo[i] = (nw + i * 16 + l16) * 32 + xq * 8;

    for (int kt = 0; kt < K; kt += 32) {
#pragma unroll
        for (int j = 0; j < NA; j++) gld_lds16(AgL[j] + kt, AsL[j]);
#pragma unroll
        for (int j = 0; j < 2; j++) gld_lds16(BgL[j] + kt, BsL[j]);
        __syncthreads();

        bf16x8 af[MI], bfr[4];
#pragma unroll
        for (int i = 0; i < MI; i++) af[i] = *(const bf16x8*)&As[afo[i]];
#pragma unroll
        for (int i = 0; i < 4; i++) bfr[i] = *(const bf16x8*)&Bs[bfo[i]];
#pragma unroll
        for (int mi = 0; mi < MI; mi++)
#pragma unroll
            for (int ni = 0; ni < 4; ni++)
                acc[mi][ni] = mfma16(af[mi], bfr[ni], acc[mi][ni]);
        __syncthreads();
    }

#pragma unroll
    for (int ni = 0; ni < 4; ni++) {
        int col = nbase + nw + ni * 16 + l16;
        float bv = bias[col];
        float scale = (SCALE_Q && col < 768) ? CST : 1.0f;
#pragma unroll
        for (int mi = 0; mi < MI; mi++) {
#pragma unroll
            for (int r = 0; r < 4; r++) {
                int row = mbase + mw + mi * 16 + quad * 4 + r;
                float v = (acc[mi][ni][r] + bv) * scale;
                if (OUT_F32)
                    ((float*)Cv)[(size_t)row * N + col] = v;
                else
                    ((u16*)Cv)[(size_t)row * N + col] = f2bf(v);
            }
        }
    }
}

// ---------------------------------------------------------------------------
// MFMA flash attention v5: LDS-free main loop.
// K and V fragments loaded directly global->VGPR (same bf16 values as the
// r8/r9 LDS path -> bit-identical math). No __syncthreads in the KV loop.
// S^T = K·Q^T keeps P in-register for PV (V pre-permuted by vtrans).
// Max-free softmax (Q pre-scaled by CST), exact cross-wave merge at end.
// ---------------------------------------------------------------------------
#define SEQ 4096
#define QKV_LD 2304

__global__ __launch_bounds__(256, 3) void attn_flash(const u16* __restrict__ qkv,
                                                     const u16* __restrict__ vt,
                                                     u16* __restrict__ attn) {
    __shared__ __align__(16) char smem[34816];   // epilogue merge scratch only
    __shared__ float Lm[4][64];

    int t = threadIdx.x;
    int wave = t >> 6, lane = t & 63, quad = lane >> 4, l16 = lane & 15;
    int h = blockIdx.y;
    int q0 = blockIdx.x * 64;
    const int QOFF = h * 64, KOFF = 768 + h * 64;

    // Q fragments (B-operand of S^T = K·Q^T)
    bf16x8 qf[4][2];
#pragma unroll
    for (int qs = 0; qs < 4; qs++) {
        const u16* qp = qkv + (size_t)(q0 + qs * 16 + l16) * QKV_LD + QOFF + quad * 8;
        qf[qs][0] = *(const bf16x8*)(qp);
        qf[qs][1] = *(const bf16x8*)(qp + 32);
    }

    f32x4 o[4][4];
    float l4[4];
#pragma unroll
    for (int qs = 0; qs < 4; qs++) {
        l4[qs] = 0.f;
#pragma unroll
        for (int j = 0; j < 4; j++) o[qs][j] = fzero();
    }

    // per-lane K/V fragment pointers (advance by tile each iteration)
    // K frag (A-op): row = kv0 + wave*32 + st*16 + l16, col = quad*8 (+32)
    const u16* kp = qkv + (size_t)(wave * 32 + l16) * QKV_LD + KOFF + quad * 8;
    // V frag (B-op): Vt row = h*64 + nt*16 + l16, col = kv0 + wave*32 + quad*8
    const u16* vp = vt + (size_t)(h * 64 + l16) * SEQ + wave * 32 + quad * 8;

    for (int kv0 = 0; kv0 < SEQ; kv0 += 128) {
        bf16x8 kf[2][2];
        kf[0][0] = *(const bf16x8*)(kp);
        kf[0][1] = *(const bf16x8*)(kp + 32);
        kf[1][0] = *(const bf16x8*)(kp + 16 * QKV_LD);
        kf[1][1] = *(const bf16x8*)(kp + 16 * QKV_LD + 32);
        bf16x8 vf[4];
#pragma unroll
        for (int nt = 0; nt < 4; nt++)
            vf[nt] = *(const bf16x8*)(vp + (size_t)nt * 16 * SEQ);
        kp += (size_t)128 * QKV_LD;
        vp += 128;

#pragma unroll
        for (int qs = 0; qs < 4; qs++) {
            f32x4 s0 = mfma16(kf[0][0], qf[qs][0], fzero());
            s0 = mfma16(kf[0][1], qf[qs][1], s0);
            f32x4 s1 = mfma16(kf[1][0], qf[qs][0], fzero());
            s1 = mfma16(kf[1][1], qf[qs][1], s1);
            float p00 = exp2f(s0[0]), p01 = exp2f(s0[1]);
            float p02 = exp2f(s0[2]), p03 = exp2f(s0[3]);
            float p10 = exp2f(s1[0]), p11 = exp2f(s1[1]);
            float p12 = exp2f(s1[2]), p13 = exp2f(s1[3]);
            l4[qs] += ((p00 + p01) + (p02 + p03)) + ((p10 + p11) + (p12 + p13));
            uint4 pk;
            pk.x = __builtin_amdgcn_perm(fbits(p01), fbits(p00), 0x07060302u);
            pk.y = __builtin_amdgcn_perm(fbits(p03), fbits(p02), 0x07060302u);
            pk.z = __builtin_amdgcn_perm(fbits(p11), fbits(p10), 0x07060302u);
            pk.w = __builtin_amdgcn_perm(fbits(p13), fbits(p12), 0x07060302u);
            bf16x8 pf;
            __builtin_memcpy(&pf, &pk, 16);
#pragma unroll
            for (int nt = 0; nt < 4; nt++)
                o[qs][nt] = mfma16(pf, vf[nt], o[qs][nt]);
        }
    }

    // ---- l: sum across the 4 quads holding q-row l16 ----
#pragma unroll
    for (int qs = 0; qs < 4; qs++) {
        l4[qs] += __shfl_xor(l4[qs], 16);
        l4[qs] += __shfl_xor(l4[qs], 32);
    }
    if (lane < 16) {
#pragma unroll
        for (int qs = 0; qs < 4; qs++) Lm[wave][qs * 16 + l16] = l4[qs];
    }

    // ---- cross-wave O merge (exact: max-free partials just add) ----
    float* M0 = (float*)smem;              // [64][68]
    float* M1 = (float*)(smem + 17408);    // [64][68]
    __syncthreads();
    if (wave >= 2) {
        float* M = (wave == 2) ? M0 : M1;
#pragma unroll
        for (int qs = 0; qs < 4; qs++)
#pragma unroll
            for (int nt = 0; nt < 4; nt++)
#pragma unroll
                for (int r = 0; r < 4; r++)
                    M[(qs * 16 + quad * 4 + r) * 68 + nt * 16 + l16] = o[qs][nt][r];
    }
    __syncthreads();
    if (wave < 2) {
        float* M = (wave == 0) ? M0 : M1;
#pragma unroll
        for (int qs = 0; qs < 4; qs++)
#pragma unroll
            for (int nt = 0; nt < 4; nt++)
#pragma unroll
                for (int r = 0; r < 4; r++)
                    o[qs][nt][r] += M[(qs * 16 + quad * 4 + r) * 68 + nt * 16 + l16];
    }
    __syncthreads();
    if (wave == 1) {
#pragma unroll
        for (int qs = 0; qs < 4; qs++)
#pragma unroll
            for (int nt = 0; nt < 4; nt++)
#pragma unroll
                for (int r = 0; r < 4; r++)
                    M0[(qs * 16 + quad * 4 + r) * 68 + nt * 16 + l16] = o[qs][nt][r];
    }
    __syncthreads();
    if (wave == 0) {
#pragma unroll
        for (int qs = 0; qs < 4; qs++) {
#pragma unroll
            for (int r = 0; r < 4; r++) {
                int rw = qs * 16 + quad * 4 + r;
                float l = Lm[0][rw] + Lm[1][rw] + Lm[2][rw] + Lm[3][rw];
                float inv = 1.0f / l;
                u16* op = attn + (size_t)(q0 + rw) * 768 + h * 64;
#pragma unroll
                for (int nt = 0; nt < 4; nt++) {
                    float v = o[qs][nt][r] + M0[rw * 68 + nt * 16 + l16];
                    op[nt * 16 + l16] = f2bf(v * inv);
                }
            }
        }
    }
}

// ---------------------------------------------------------------------------
extern "C" void kernel_launch(void* const* d_in, const int* in_sizes, int n_in,
                              void* d_out, int out_size, void* d_ws, size_t ws_size,
                              hipStream_t stream) {
    const float* x      = (const float*)d_in[0];  // [4096][768] fp32
    const float* w_qkv  = (const float*)d_in[1];  // [768][2304] fp32
    const float* b_qkv  = (const float*)d_in[2];  // [2304] fp32
    const float* w_o    = (const float*)d_in[3];  // [768][768] fp32
    const float* b_o    = (const float*)d_in[4];  // [768] fp32
    float* out = (float*)d_out;                   // [4096][768] fp32

    u16* wqkvT = (u16*)d_ws;                       // [2304][768] bf16  3.54 MB
    u16* woT   = wqkvT + (size_t)2304 * 768;       // [768][768]  bf16  1.18 MB
    u16* qkv   = woT + (size_t)768 * 768;          // [4096][2304] bf16 18.87 MB
    u16* attnb = qkv + (size_t)4096 * 2304;        // [4096][768] bf16  6.29 MB
    u16* Vt    = attnb + (size_t)4096 * 768;       // [12*64][4096] bf16 6.29 MB
    u16* xb    = attnb;  // aliases attnb: xb dead before attn writes attnb
    // total 36.17 MB == r5-r9 footprint

    prep<<<dim3(NB_WQKV + NB_WO + NB_CVT), 256, 0, stream>>>(
        x, w_qkv, w_o, xb, wqkvT, woT);

    gemm_bt<128, false, true><<<dim3(2304 / 128, 4096 / 128), 256, 0, stream>>>(
        xb, wqkvT, b_qkv, qkv, 4096, 2304, 768);

    vtrans<<<dim3(SEQ / 128, 12), 256, 0, stream>>>(qkv, Vt);

    attn_flash<<<dim3(SEQ / 64, 12), 256, 0, stream>>>(qkv, Vt, attnb);

    gemm_bt<64, true, false><<<dim3(768 / 128, 4096 / 64), 256, 0, stream>>>(
        attnb, woT, b_o, out, 4096, 768, 768);
}